// Round 9
// baseline (87.375 us; speedup 1.0000x reference)
//
#include <hip/hip_runtime.h>
#include <stdint.h>

// Pipeline (k' = (ky*2+kx)*256 + c ordering for the GEMM K axis):
//   0. prep : blocks 0..511    -> W fp32 -> Wq in GEMM-staging order bf16 (BK=32 tiles)
//             blocks 512..4607 -> img (8,256,128,128) fp32 -> imgT[b][y][x][c] bf16
//   1. gemm : 256x256-tile 8-wave MFMA GEMM, BK=32, QUAD-buffered LDS,
//             3-tile prefetch depth, counted vmcnt(8) (never 0 until drain),
//             ONE barrier per K-tile, A gathered in-staging from imgT.
//      pixel (py,px) <-> (o,p): o=(py>>1)+2*(px>>1), p=(py&1)*2+(px&1)
// Wq layout: [et:4][jt:32][chunk:4][row:256][8 k] -> staging inst = fully coalesced,
//   ds_read af conflict-free (bank = row*4).

typedef __attribute__((ext_vector_type(8))) short bf16x8;
typedef __attribute__((ext_vector_type(4))) float f32x4;

#define GAS(p) ((const __attribute__((address_space(1))) void*)(p))
#define LAS(p) ((__attribute__((address_space(3))) void*)(p))

__device__ __forceinline__ unsigned short f2bf(float f) {
    union { float f; uint32_t u; } x; x.f = f;
    uint32_t u = x.u;
    uint32_t r = (u + 0x7FFFu + ((u >> 16) & 1u)) >> 16;   // round-nearest-even
    return (unsigned short)r;
}

// ---------------- Stage 0: fused W-reorder (staging order) + img transpose ----------------
__global__ __launch_bounds__(256)
void prep_kernel(const float* __restrict__ img, const float* __restrict__ Wf,
                 unsigned short* __restrict__ Wq, unsigned short* __restrict__ zp,
                 unsigned short* __restrict__ imgT) {
    __shared__ unsigned short sT[8192];
    const int blk = blockIdx.x;
    const int tid = threadIdx.x;

    if (blk < 512) {                        // ---- Wq: thread = 8 k's of (et,jt,chunk,row)
        if (blk == 0 && tid < 32) {
            uint4 z = {0, 0, 0, 0};
            ((uint4*)zp)[tid] = z;          // 512 B zeros for OOB staging
        }
        const int t  = blk * 256 + tid;     // 0..131071
        const int et = t >> 15;
        const int r1 = t & 32767;
        const int jt = r1 >> 10;            // K-tile of 32
        const int r2 = r1 & 1023;
        const int chunk = r2 >> 8;
        const int row   = r2 & 255;
        const int e  = et * 256 + row;
        const int kb = jt * 32 + chunk * 8;
        unsigned short v[8];
        #pragma unroll
        for (int kk = 0; kk < 8; ++kk) {
            const int k = kb + kk;          // k' in [0,1024)
            const int c = k & 255;
            const int p = k >> 8;
            v[kk] = f2bf(Wf[(size_t)e * 1024 + c * 4 + p]);
        }
        *(uint4*)&Wq[(size_t)t * 8] = *(const uint4*)v;
        return;
    }

    // ---- imgt: block = (b, y, c-chunk of 64); float4-vectorized reads ----
    const int ib = blk - 512;               // 0..4095
    const int cc = ib & 3;
    const int y  = (ib >> 2) & 127;
    const int b  = ib >> 9;
    const int xq = tid & 31;                // x-quad: x = xq*4 + jj
    const int ch = tid >> 5;                // 0..7 (c-pair subgroup)
    unsigned int* sU = (unsigned int*)sT;
    const size_t pl = ((size_t)b * 256 + cc * 64) * 16384 + (size_t)y * 128;
    #pragma unroll
    for (int it = 0; it < 4; ++it) {
        const int cp = it * 8 + ch;         // c-pair 0..31
        const float4 v0 = *(const float4*)&img[pl + (size_t)(2 * cp)     * 16384 + xq * 4];
        const float4 v1 = *(const float4*)&img[pl + (size_t)(2 * cp + 1) * 16384 + xq * 4];
        const float a0[4] = {v0.x, v0.y, v0.z, v0.w};
        const float a1[4] = {v1.x, v1.y, v1.z, v1.w};
        #pragma unroll
        for (int jj = 0; jj < 4; ++jj) {
            const int x = xq * 4 + jj;
            const unsigned int pk = (unsigned)f2bf(a0[jj]) | ((unsigned)f2bf(a1[jj]) << 16);
            sU[x * 32 + (cp ^ (x & 31))] = pk;
        }
    }
    __syncthreads();
    unsigned short* ob = imgT + (((size_t)b * 128 + y) * 128) * 256 + cc * 64;
    #pragma unroll
    for (int jj = 0; jj < 16; ++jj) {
        const int oo = tid + 256 * jj;      // 0..4095
        const int xx = oo >> 5;
        const int c2 = oo & 31;
        const unsigned int pk = sU[xx * 32 + (c2 ^ (xx & 31))];
        *(unsigned int*)&ob[(size_t)xx * 256 + c2 * 2] = pk;
    }
}

// ---------------- Stage 1: fused-gather 256^2 MFMA GEMM, BK=32, quad-buffered ----------------
// 256 blocks (1/CU), 512 threads (8 waves 2m x 4n). 32 K-tiles of 32.
// Per wave per tile: 4 staged insts (2 W + 2 A). Prologue stages 3 tiles;
// steady state waits vmcnt(8) (2 tiles in flight, ~750cy cover), 1 barrier/tile.
__global__ __launch_bounds__(512, 1)
void gemm_kernel(const unsigned short* __restrict__ Wq,
                 const unsigned short* __restrict__ imgT,
                 const unsigned short* __restrict__ zp,
                 const int* __restrict__ bidx,
                 const int* __restrict__ pxid,
                 const int* __restrict__ pyid,
                 const float* __restrict__ bias,
                 float* __restrict__ out)
{
    const int orig = blockIdx.x;            // 256
    const int xcd  = orig & 7;
    const int s    = orig >> 3;             // 0..31
    const int gnt  = xcd * 8 + (s >> 2);    // 64 gn-tiles of 256; e-siblings share XCD
    const int et   = s & 3;                 // 4 e-tiles of 256
    const int e0   = et * 256;
    const int g    = gnt >> 1;
    const int n0   = (gnt & 1) * 256;
    const int b = g >> 2, o = g & 3;

    const int tid  = threadIdx.x;
    const int lane = tid & 63;
    const int wid  = tid >> 6;
    const int wm   = wid >> 2;              // 0..1 -> e rows wm*128
    const int wn   = wid & 3;               // 0..3 -> n cols wn*64

    __shared__ unsigned short sW[4][8192];  // [buf][chunk:4][row:256][8]  64 KB
    __shared__ unsigned short sA[4][8192];  // [buf][row:256][slot:4][8]   64 KB

    // ---- A stage descriptors: thread -> rows u*128 + tid/4, 16B slot (tid&3) ----
    int ayv[2], axv[2];
    size_t apl[2];
    #pragma unroll
    for (int u = 0; u < 2; ++u) {
        const int row = u * 128 + (tid >> 2);
        const int gi = b * 512 + n0 + row;
        apl[u] = (size_t)bidx[gi] * (128 * 128 * 256);
        ayv[u] = 2 * pyid[gi] - 1 + (o & 1) * 2;   // + (p>>1) at stage time
        axv[u] = 2 * pxid[gi] - 1 + (o >> 1) * 2;  // + (p&1)
    }
    const int aswz = (((tid & 3) ^ ((tid >> 3) & 3))) * 8;  // pre-swizzled slot (shorts)
    const unsigned short* wq_base = Wq + (size_t)et * 262144 + tid * 8;

    f32x4 acc[8][4];
    #pragma unroll
    for (int m = 0; m < 8; ++m)
        #pragma unroll
        for (int nf = 0; nf < 4; ++nf) acc[m][nf] = (f32x4){0.f, 0.f, 0.f, 0.f};

    auto stage = [&](int jt, int buf) {
        // W: 2 fully-coalesced insts from Wq staging order
        #pragma unroll
        for (int u = 0; u < 2; ++u)
            __builtin_amdgcn_global_load_lds(GAS(wq_base + (size_t)jt * 8192 + u * 4096),
                LAS(&sW[buf][u * 4096 + tid * 8]), 16, 0, 0);
        // A: 2 insts; tile jt covers 64B window (jt&7)*64 of pixel row, plane p=jt>>3
        const int p   = jt >> 3;
        const int csh = (jt & 7) * 32 + aswz;      // shorts
        #pragma unroll
        for (int u = 0; u < 2; ++u) {
            const int yy = ayv[u] + (p >> 1);
            const int xx = axv[u] + (p & 1);
            const unsigned short* src =
                ((unsigned)yy < 128u && (unsigned)xx < 128u)
                    ? imgT + apl[u] + ((size_t)(yy * 128 + xx)) * 256 + csh
                    : zp + aswz;
            __builtin_amdgcn_global_load_lds(GAS(src),
                LAS(&sA[buf][u * 4096 + tid * 8]), 16, 0, 0);
        }
    };

    // prologue: 3 tiles staged (12 insts in flight per wave)
    stage(0, 0);
    stage(1, 1);
    stage(2, 2);

    for (int j = 0; j < 32; ++j) {
        const int buf = j & 3;
        // complete tile j; keep tiles j+1, j+2 (8 insts) in flight
        if (j < 30)      { asm volatile("s_waitcnt vmcnt(8)" ::: "memory"); }
        else if (j == 30){ asm volatile("s_waitcnt vmcnt(4)" ::: "memory"); }
        else             { asm volatile("s_waitcnt vmcnt(0)" ::: "memory"); }
        __builtin_amdgcn_s_barrier();
        if (j + 3 < 32) stage(j + 3, (j + 3) & 3);   // deep prefetch

        // W fragments (K=32): lane's k-chunk = lane>>4
        bf16x8 af[8];
        {
            const int chunk = lane >> 4;
            const int rb = wm * 128 + (lane & 15);
            #pragma unroll
            for (int m = 0; m < 8; ++m)
                af[m] = *(const bf16x8*)&sW[buf][chunk * 2048 + (rb + m * 16) * 8];
        }
        #pragma unroll
        for (int nh = 0; nh < 2; ++nh) {
            bf16x8 bfr[2];
            #pragma unroll
            for (int nn = 0; nn < 2; ++nn) {
                const int row = wn * 64 + (nh * 2 + nn) * 16 + (lane & 15);
                const int perm = (lane >> 4) ^ ((row >> 1) & 3);
                bfr[nn] = *(const bf16x8*)&sA[buf][row * 32 + perm * 8];
            }
            __builtin_amdgcn_s_setprio(1);
            #pragma unroll
            for (int m = 0; m < 8; ++m)
                #pragma unroll
                for (int nn = 0; nn < 2; ++nn)
                    acc[m][nh * 2 + nn] = __builtin_amdgcn_mfma_f32_16x16x32_bf16(
                        af[m], bfr[nn], acc[m][nh * 2 + nn], 0, 0, 0);
            __builtin_amdgcn_s_setprio(0);
        }
    }

    // ---- epilogue: D row(e) = (lane>>4)*4+reg, col(n) = lane&15 ----
    #pragma unroll
    for (int m = 0; m < 8; ++m) {
        const int eb = e0 + wm * 128 + m * 16 + (lane >> 4) * 4;
        float bv[4];
        #pragma unroll
        for (int reg = 0; reg < 4; ++reg) bv[reg] = bias[eb + reg];
        #pragma unroll
        for (int nf = 0; nf < 4; ++nf) {
            const int nn = n0 + wn * 64 + nf * 16 + (lane & 15);
            #pragma unroll
            for (int reg = 0; reg < 4; ++reg)
                out[((size_t)g * 1024 + eb + reg) * 512 + nn] = acc[m][nf][reg] + bv[reg];
        }
    }
}

extern "C" void kernel_launch(void* const* d_in, const int* in_sizes, int n_in,
                              void* d_out, int out_size, void* d_ws, size_t ws_size,
                              hipStream_t stream) {
    const float* img  = (const float*)d_in[0];
    const float* Wf   = (const float*)d_in[1];
    const float* bias = (const float*)d_in[2];
    const int*   bidx = (const int*)d_in[3];
    const int*   pxid = (const int*)d_in[4];
    const int*   pyid = (const int*)d_in[5];
    float* out = (float*)d_out;

    unsigned short* Wq   = (unsigned short*)((char*)d_ws + (32u << 20));  // 2 MiB
    unsigned short* zp   = (unsigned short*)((char*)d_ws + (36u << 20));  // 512 B zeros
    unsigned short* imgT = (unsigned short*)((char*)d_ws + (64u << 20));  // 64 MiB

    hipLaunchKernelGGL(prep_kernel, dim3(4608), dim3(256), 0, stream,
                       img, Wf, Wq, zp, imgT);
    hipLaunchKernelGGL(gemm_kernel, dim3(256), dim3(512), 0, stream,
                       Wq, imgT, zp, bidx, pxid, pyid, bias, out);
}